// Round 1
// baseline (568.079 us; speedup 1.0000x reference)
//
#include <hip/hip_runtime.h>
#include <hip/hip_bf16.h>

// GCN 3-layer. CSR via LDS-binned partition into fixed-capacity bucket
// windows. bf16 MFMA GEMM + bf16 gather (8-deep batched loads).
// Layer-3 hs packed at stride 40 (no pad fetch in the 40-dim gather).
// This round: 4 partition kernels fused into ONE persistent kernel with a
// manual device-scope grid barrier (391 blocks co-resident via
// __launch_bounds__(256,2): 391 <= 512 capacity). Saves 3 launch gaps +
// small-kernel ramp bubbles. agg4: dinv/bias prefetched above the edge
// loop (latency off the epilogue critical path).
// NOTE: degree-sorted perm stays REVERTED (replay-unstable — see round-10).

constexpr int BLK = 256;
constexpr int SB2 = 9;                  // bucket = 512 nodes
constexpr int EPB = 4096;               // edges per partition block
constexpr int BUCKCAP = 10240;          // bucket window capacity (mean 8192, +22 sigma)
// packed partition word: (local_node_id << 23) | src   (requires N < 2^23)

typedef __attribute__((ext_vector_type(8))) short bf16x8;   // 8 bf16 = 4 VGPR
typedef __attribute__((ext_vector_type(4))) float f32x4;    // MFMA acc

__device__ inline unsigned short bf_rne(float f) {
    unsigned int u = __float_as_uint(f);
    unsigned int r = (u + 0x7fffu + ((u >> 16) & 1u)) >> 16;
    return (unsigned short)r;
}
__device__ inline unsigned int pk(unsigned short lo, unsigned short hi) {
    return (unsigned int)lo | ((unsigned int)hi << 16);
}

// Device-scope grid barrier. All blocks must be co-resident (guaranteed by
// __launch_bounds__(256,2) with grid <= 512). Counter monotonically
// increases; zeroed by hipMemsetAsync before launch. threadfence on the
// release side flushes this block's stores agent-wide (covers per-XCD L2
// non-coherence); threadfence on the acquire side invalidates before the
// next phase reads other blocks' output.
__device__ inline void gridbar(int* bar, int target) {
    __threadfence();                        // release: my stores -> device
    __syncthreads();
    if (threadIdx.x == 0) {
        __hip_atomic_fetch_add(bar, 1, __ATOMIC_ACQ_REL, __HIP_MEMORY_SCOPE_AGENT);
        while (__hip_atomic_load(bar, __ATOMIC_RELAXED, __HIP_MEMORY_SCOPE_AGENT) < target)
            __builtin_amdgcn_s_sleep(1);
    }
    __syncthreads();
    __threadfence();                        // acquire: see others' stores
}

// ---------- fused partition: hist | scan | scatter | finalize ----------
__global__ __launch_bounds__(256, 2) void partition_all(
    const int* __restrict__ src, const int* __restrict__ dst,
    int* __restrict__ bh, int* __restrict__ btot,
    unsigned int* __restrict__ buf,
    int* __restrict__ rptr, int* __restrict__ rdeg, float* __restrict__ dinv,
    int* __restrict__ csr, int* __restrict__ bar,
    int E, int nblk, int NB2, int N)
{
    __shared__ int smA[512];      // P1 hist / P3 lbase / P4 node-hist
    __shared__ int smB[512];      // P3 lcnt  / P4 excl
    __shared__ int smC[256];      // P2,P4 scan
    const int k = blockIdx.x, t = threadIdx.x;

    // ---- P1: per-block histogram of dst>>SB2 (int4 reads) ----
    smA[t] = 0;
    __syncthreads();
    {
        const int4* dp = (const int4*)(dst + k * EPB);
#pragma unroll
        for (int j = 0; j < EPB / 1024; ++j) {
            int idx = j * 256 + t;
            int e = k * EPB + idx * 4;
            if (e < E) {                  // E % 4 == 0 -> whole int4 valid
                int4 d4 = dp[idx];
                atomicAdd(&smA[d4.x >> SB2], 1);
                atomicAdd(&smA[d4.y >> SB2], 1);
                atomicAdd(&smA[d4.z >> SB2], 1);
                atomicAdd(&smA[d4.w >> SB2], 1);
            }
        }
    }
    __syncthreads();
    if (t < NB2) bh[t * nblk + k] = smA[t];

    gridbar(bar, nblk);

    // ---- P2: per bucket, exclusive scan over blocks; base = k*BUCKCAP ----
    if (k < NB2) {
        int base = k * BUCKCAP;
        int i0 = t * 4;
        int v0 = (i0     < nblk) ? bh[k * nblk + i0    ] : 0;
        int v1 = (i0 + 1 < nblk) ? bh[k * nblk + i0 + 1] : 0;
        int v2 = (i0 + 2 < nblk) ? bh[k * nblk + i0 + 2] : 0;
        int v3 = (i0 + 3 < nblk) ? bh[k * nblk + i0 + 3] : 0;
        int s = v0 + v1 + v2 + v3;
        smC[t] = s;
        __syncthreads();
        for (int off = 1; off < 256; off <<= 1) {
            int x = (t >= off) ? smC[t - off] : 0;
            __syncthreads();
            smC[t] += x;
            __syncthreads();
        }
        int run = smC[t] - s;
        if (t == 255) btot[k] = (smC[255] < BUCKCAP) ? smC[255] : BUCKCAP;
        if (i0     < nblk) bh[k * nblk + i0    ] = base + run; run += v0;
        if (i0 + 1 < nblk) bh[k * nblk + i0 + 1] = base + run; run += v1;
        if (i0 + 2 < nblk) bh[k * nblk + i0 + 2] = base + run; run += v2;
        if (i0 + 3 < nblk) bh[k * nblk + i0 + 3] = base + run;
    }

    gridbar(bar, 2 * nblk);

    // ---- P3: scatter packed (local,src) into private (block,bucket) runs ----
    smB[t] = 0;                                  // lcnt
    if (t < NB2) smA[t] = bh[t * nblk + k];      // lbase
    __syncthreads();
    {
        const int4* dp = (const int4*)(dst + k * EPB);
        const int4* sp = (const int4*)(src + k * EPB);
#pragma unroll
        for (int j = 0; j < EPB / 1024; ++j) {
            int idx = j * 256 + t;
            int e = k * EPB + idx * 4;
            if (e < E) {
                int4 d4 = dp[idx];
                int4 s4 = sp[idx];
                int d, bkt, p;
                d = d4.x; bkt = d >> SB2; p = smA[bkt] + atomicAdd(&smB[bkt], 1);
                buf[p] = ((unsigned int)(d & 511) << 23) | (unsigned int)s4.x;
                d = d4.y; bkt = d >> SB2; p = smA[bkt] + atomicAdd(&smB[bkt], 1);
                buf[p] = ((unsigned int)(d & 511) << 23) | (unsigned int)s4.y;
                d = d4.z; bkt = d >> SB2; p = smA[bkt] + atomicAdd(&smB[bkt], 1);
                buf[p] = ((unsigned int)(d & 511) << 23) | (unsigned int)s4.z;
                d = d4.w; bkt = d >> SB2; p = smA[bkt] + atomicAdd(&smB[bkt], 1);
                buf[p] = ((unsigned int)(d & 511) << 23) | (unsigned int)s4.w;
            }
        }
    }

    gridbar(bar, 3 * nblk);

    // ---- P4: per bucket — node hist, scan, rptr/rdeg/dinv, csr scatter ----
    if (k < NB2) {
        int nb0 = k << SB2;
        int nn = N - nb0; if (nn > (1 << SB2)) nn = 1 << SB2;
        int beg = k * BUCKCAP;
        int end = beg + btot[k];

        smA[t] = 0; smA[t + 256] = 0;
        __syncthreads();
        for (int i = beg + t; i < end; i += 256)
            atomicAdd(&smA[buf[i] >> 23], 1);
        __syncthreads();

        int a0 = smA[2 * t], a1 = smA[2 * t + 1];
        int s = a0 + a1;
        smC[t] = s;
        __syncthreads();
        for (int off = 1; off < 256; off <<= 1) {
            int x = (t >= off) ? smC[t - off] : 0;
            __syncthreads();
            smC[t] += x;
            __syncthreads();
        }
        int run = smC[t] - s;
        smB[2 * t] = run;
        smB[2 * t + 1] = run + a0;
        __syncthreads();

        for (int j = t; j < nn; j += 256) {
            rptr[nb0 + j] = beg + smB[j];
            rdeg[nb0 + j] = smA[j];
            dinv[nb0 + j] = rsqrtf((float)smA[j] + 1.0f);   // +1 self-loop
        }
        __syncthreads();

        smA[t] = 0; smA[t + 256] = 0;
        __syncthreads();
        for (int i = beg + t; i < end; i += 256) {
            unsigned int w = buf[i];
            int local = w >> 23;
            int p = beg + smB[local] + atomicAdd(&smA[local], 1);
            csr[p] = (int)(w & 0x7fffffu);
        }
    }
}

// ---------- MFMA GEMM: hs(bf16, stride HSTRIDE) = (A @ W) * d_inv[row] ----------
template<int K, int NOUT, int HSTRIDE, bool AFP32>
__global__ __launch_bounds__(256) void gemm_mfma(
    const void* __restrict__ Aptr, const float* __restrict__ W,
    const float* __restrict__ d_inv, unsigned short* __restrict__ hs, int M)
{
    __shared__ unsigned short Wt[64][K + 8];   // [col][k], +8 pad: <=2-way LDS alias
    __shared__ float Cst[64][68];              // epilogue staging

    const int t = threadIdx.x;
    const int wave = t >> 6, lane = t & 63;
    const int m = lane & 15, kq = lane >> 4;

    for (int idx = t; idx < K * 64; idx += 256) {
        int k = idx >> 6, c = idx & 63;
        float wv = (c < NOUT) ? W[k * NOUT + c] : 0.0f;
        Wt[c][k] = bf_rne(wv);
    }
    __syncthreads();

    const int rb = blockIdx.x * 64;
    int arow = rb + wave * 16 + m;
    if (arow >= M) arow = M - 1;               // clamp (stores are guarded)

    f32x4 acc[4] = {{0.f,0.f,0.f,0.f},{0.f,0.f,0.f,0.f},
                    {0.f,0.f,0.f,0.f},{0.f,0.f,0.f,0.f}};
    union Frag { bf16x8 v; unsigned short u[8]; };

#pragma unroll
    for (int kc = 0; kc < K / 32; ++kc) {
        const int kbase = kc * 32 + kq * 8;
        Frag a;
        if (AFP32) {
            const float* ap = (const float*)Aptr + (size_t)arow * K + kbase;
            float4 x0 = *(const float4*)ap;
            float4 x1 = *(const float4*)(ap + 4);
            a.u[0] = bf_rne(x0.x); a.u[1] = bf_rne(x0.y);
            a.u[2] = bf_rne(x0.z); a.u[3] = bf_rne(x0.w);
            a.u[4] = bf_rne(x1.x); a.u[5] = bf_rne(x1.y);
            a.u[6] = bf_rne(x1.z); a.u[7] = bf_rne(x1.w);
        } else {
            const unsigned short* ap = (const unsigned short*)Aptr + (size_t)arow * 64 + kbase;
            a.v = *(const bf16x8*)ap;
        }
#pragma unroll
        for (int ct = 0; ct < 4; ++ct) {
            Frag b;
            b.v = *(const bf16x8*)(&Wt[ct * 16 + m][kbase]);
            acc[ct] = __builtin_amdgcn_mfma_f32_16x16x32_bf16(a.v, b.v, acc[ct], 0, 0, 0);
        }
    }

#pragma unroll
    for (int ct = 0; ct < 4; ++ct)
#pragma unroll
        for (int r = 0; r < 4; ++r)
            Cst[wave * 16 + kq * 4 + r][ct * 16 + m] = acc[ct][r];
    __syncthreads();

    int row = t >> 2, seg = t & 3;
    int grow = rb + row;
    int c0 = seg * 16;
    if (grow < M && c0 < NOUT) {
        float di = d_inv[grow];
        unsigned int uu[8];
#pragma unroll
        for (int j = 0; j < 8; ++j) {
            float v0 = Cst[row][c0 + 2 * j]     * di;
            float v1 = Cst[row][c0 + 2 * j + 1] * di;
            uu[j] = pk(bf_rne(v0), bf_rne(v1));
        }
        unsigned short* orow = hs + (size_t)grow * HSTRIDE + c0;
        *(uint4*)orow = make_uint4(uu[0], uu[1], uu[2], uu[3]);
        if (NOUT - c0 > 8)
            *((uint4*)orow + 1) = make_uint4(uu[4], uu[5], uu[6], uu[7]);
    }
}

// ---------- fused aggregate + epilogue: quarter-wave per node ----------
// lane = sub*16 + q. Lane owns dims [q*4, q*4+4): private accumulate, no
// reduce. Gather batched 8-deep: 8 independent loads in flight per lane.
// dinv/bias prefetched above the edge loop (latency hides under gathers).
template<int DACT, int HSTRIDE, bool RELU, bool OBF16, int OSTRIDE>
__global__ __launch_bounds__(256) void agg4(
    const unsigned short* __restrict__ hs, const int* __restrict__ rptr,
    const int* __restrict__ rdeg, const int* __restrict__ csr,
    const float* __restrict__ dinv, const float* __restrict__ b,
    void* __restrict__ out, int N)
{
    int i = (blockIdx.x * 256 + threadIdx.x) >> 4;     // node per quarter-wave
    if (i >= N) return;
    int lane = threadIdx.x & 63;
    int q  = lane & 15;                                 // dim quad
    int sb = lane & 48;                                 // subgroup base lane
    constexpr int QACT = DACT / 4;                      // active quads (16 or 10)
    const bool act = (q < QACT);

    int beg = rptr[i];
    int end = beg + rdeg[i];

    float a0 = 0.f, a1 = 0.f, a2 = 0.f, a3 = 0.f;
    float di = 0.f;
    float4 bv = make_float4(0.f, 0.f, 0.f, 0.f);
    if (act) {                                          // self-loop init + prefetch
        di = dinv[i];
        bv = *(const float4*)(b + q * 4);
        uint2 u0 = *(const uint2*)(hs + (size_t)i * HSTRIDE + q * 4);
        a0 = __uint_as_float(u0.x << 16);
        a1 = __uint_as_float(u0.x & 0xffff0000u);
        a2 = __uint_as_float(u0.y << 16);
        a3 = __uint_as_float(u0.y & 0xffff0000u);
    }

    for (int c = beg; c < end; c += 16) {
        int s_l = (c + q < end) ? csr[c + q] : 0;      // coalesced 64B prefetch
        int m = end - c; if (m > 16) m = 16;
        int k = 0;
        for (; k + 8 <= m; k += 8) {                   // 8 loads in flight
            int ss[8];
#pragma unroll
            for (int j = 0; j < 8; ++j) ss[j] = __shfl(s_l, sb | (k + j), 64);
            if (act) {
                uint2 vv[8];
#pragma unroll
                for (int j = 0; j < 8; ++j)
                    vv[j] = *(const uint2*)(hs + (size_t)ss[j] * HSTRIDE + q * 4);
#pragma unroll
                for (int j = 0; j < 8; ++j) {
                    a0 += __uint_as_float(vv[j].x << 16);
                    a1 += __uint_as_float(vv[j].x & 0xffff0000u);
                    a2 += __uint_as_float(vv[j].y << 16);
                    a3 += __uint_as_float(vv[j].y & 0xffff0000u);
                }
            }
        }
        for (; k < m; ++k) {
            int s = __shfl(s_l, sb | k, 64);
            if (act) {
                uint2 u = *(const uint2*)(hs + (size_t)s * HSTRIDE + q * 4);
                a0 += __uint_as_float(u.x << 16);
                a1 += __uint_as_float(u.x & 0xffff0000u);
                a2 += __uint_as_float(u.y << 16);
                a3 += __uint_as_float(u.y & 0xffff0000u);
            }
        }
    }

    if (act) {
        a0 = di * a0 + bv.x; a1 = di * a1 + bv.y;
        a2 = di * a2 + bv.z; a3 = di * a3 + bv.w;
        if (RELU) {
            a0 = fmaxf(a0, 0.f); a1 = fmaxf(a1, 0.f);
            a2 = fmaxf(a2, 0.f); a3 = fmaxf(a3, 0.f);
        }
        if (OBF16) {
            unsigned short* ob = (unsigned short*)out;
            uint2 o;
            o.x = pk(bf_rne(a0), bf_rne(a1));
            o.y = pk(bf_rne(a2), bf_rne(a3));
            *(uint2*)(ob + (size_t)i * 64 + q * 4) = o;
        } else {
            float* of = (float*)out;
            *(float4*)(of + (size_t)i * OSTRIDE + q * 4) = make_float4(a0, a1, a2, a3);
        }
    }
}

extern "C" void kernel_launch(void* const* d_in, const int* in_sizes, int n_in,
                              void* d_out, int out_size, void* d_ws, size_t ws_size,
                              hipStream_t stream) {
    const float* x   = (const float*)d_in[0];
    const int*   ei  = (const int*)  d_in[1];
    const float* W1  = (const float*)d_in[2];
    const float* bb1 = (const float*)d_in[3];
    const float* W2  = (const float*)d_in[4];
    const float* bb2 = (const float*)d_in[5];
    const float* W3  = (const float*)d_in[6];
    const float* bb3 = (const float*)d_in[7];
    float* out = (float*)d_out;

    const int N = in_sizes[0] / 128;      // 100000
    const int E = in_sizes[1] / 2;        // 1600000
    const int* src = ei;
    const int* dst = ei + E;
    const int NB2  = (N + (1 << SB2) - 1) >> SB2;   // 196 buckets (<=256)
    const int nblk = (E + EPB - 1) / EPB;           // 391 partition blocks (<=512 co-resident)

    // workspace layout (4-byte units)
    float* ws = (float*)d_ws;
    const size_t NP  = ((size_t)N + 255) & ~255ull;
    float* dinv = ws;                                   // NP
    unsigned short* bufHs  = (unsigned short*)(ws + NP);        // N*64 bf16
    unsigned short* bufAct = bufHs + (size_t)N * 64;            // N*64 bf16
    int*   rptr  = (int*)(bufAct + (size_t)N * 64);     // N
    int*   rdeg  = rptr + N;                            // N
    int*   btot  = rdeg + N;                            // NB2 (pad 256)
    int*   bh    = btot + 256;                          // NB2*nblk
    size_t bhsz  = ((size_t)NB2 * nblk + 1) & ~1ull;
    unsigned int* buf = (unsigned int*)(bh + bhsz);     // NB2*BUCKCAP
    int*   csr   = (int*)(buf + (size_t)NB2 * BUCKCAP); // NB2*BUCKCAP
    int*   bar   = csr + (size_t)NB2 * BUCKCAP;         // 4 ints (grid barrier)

    dim3 blk(BLK);
    int gRows = (N + 63) / 64;
    int gQW   = (N * 16 + BLK - 1) / BLK;    // quarter-wave per node

    // ---- binned partition -> CSR + degrees (single fused kernel) ----
    hipMemsetAsync(bar, 0, 16, stream);      // barrier counter (ws is poisoned)
    partition_all<<<nblk, blk, 0, stream>>>(src, dst, bh, btot, buf,
                                            rptr, rdeg, dinv, csr, bar,
                                            E, nblk, NB2, N);

    // ---- layer 1: 128 -> 64, relu ----
    gemm_mfma<128, 64, 64, true><<<gRows, blk, 0, stream>>>(x, W1, dinv, bufHs, N);
    agg4<64, 64, true, true, 64><<<gQW, blk, 0, stream>>>(bufHs, rptr, rdeg, csr, dinv, bb1, bufAct, N);

    // ---- layer 2: 64 -> 64, relu ----
    gemm_mfma<64, 64, 64, false><<<gRows, blk, 0, stream>>>(bufAct, W2, dinv, bufHs, N);
    agg4<64, 64, true, true, 64><<<gQW, blk, 0, stream>>>(bufHs, rptr, rdeg, csr, dinv, bb2, bufAct, N);

    // ---- layer 3: 64 -> 40 packed stride-40, no relu ----
    gemm_mfma<64, 40, 40, false><<<gRows, blk, 0, stream>>>(bufAct, W3, dinv, bufHs, N);
    agg4<40, 40, false, false, 40><<<gQW, blk, 0, stream>>>(bufHs, rptr, rdeg, csr, dinv, bb3, out, N);
}

// Round 2
// 284.052 us; speedup vs baseline: 1.9999x; 1.9999x over previous
//
#include <hip/hip_runtime.h>
#include <hip/hip_bf16.h>

// GCN 3-layer. CSR via LDS-binned partition into fixed-capacity bucket
// windows. bf16 MFMA GEMM + bf16 gather (8-deep batched loads).
// Layer-3 hs packed at stride 40 (no pad fetch in the 40-dim gather).
// NOTE: round-10's degree-sorted perm REVERTED (replay-unstable).
// NOTE: round-1's persistent-kernel fused partition REVERTED — per-block
// __threadfence() in the grid barrier lowers to an L2 writeback-invalidate
// (buffer_wbl2) on gfx950: 391 blocks x 3 barriers produced 41.8 GB of HBM
// writes and 338 us in partition_all alone. 4-kernel chain is cheaper:
// kernel-boundary coherence is one pipelined CP-managed flush, not O(blocks).

constexpr int BLK = 256;
constexpr int SB2 = 9;                  // bucket = 512 nodes
constexpr int EPB = 4096;               // edges per partition block
constexpr int BUCKCAP = 10240;          // bucket window capacity (mean 8192, +22 sigma)
// packed partition word: (local_node_id << 23) | src   (requires N < 2^23)

typedef __attribute__((ext_vector_type(8))) short bf16x8;   // 8 bf16 = 4 VGPR
typedef __attribute__((ext_vector_type(4))) float f32x4;    // MFMA acc

__device__ inline unsigned short bf_rne(float f) {
    unsigned int u = __float_as_uint(f);
    unsigned int r = (u + 0x7fffu + ((u >> 16) & 1u)) >> 16;
    return (unsigned short)r;
}
__device__ inline unsigned int pk(unsigned short lo, unsigned short hi) {
    return (unsigned int)lo | ((unsigned int)hi << 16);
}

// ---------- Pass A: per-block histogram of dst>>SB2 (int4 reads) ----------
__global__ __launch_bounds__(256) void part_hist(
    const int* __restrict__ dst, int* __restrict__ bh, int E, int nblk, int NB2) {
    __shared__ int lh[256];               // NB2 <= 256
    int k = blockIdx.x, t = threadIdx.x;
    lh[t] = 0;
    __syncthreads();
    const int4* dp = (const int4*)(dst + k * EPB);
#pragma unroll
    for (int j = 0; j < EPB / 1024; ++j) {
        int idx = j * 256 + t;            // int4 index within block
        int e = k * EPB + idx * 4;
        if (e < E) {                      // E % 4 == 0 -> whole int4 valid
            int4 d4 = dp[idx];
            atomicAdd(&lh[d4.x >> SB2], 1);
            atomicAdd(&lh[d4.y >> SB2], 1);
            atomicAdd(&lh[d4.z >> SB2], 1);
            atomicAdd(&lh[d4.w >> SB2], 1);
        }
    }
    __syncthreads();
    if (t < NB2) bh[t * nblk + k] = lh[t];
}

// ---------- Pass A': per bucket, exclusive scan over blocks; base = b*BUCKCAP ----------
__global__ __launch_bounds__(256) void part_scan(
    int* __restrict__ bh, int* __restrict__ btot, int nblk) {
    __shared__ int sh[256];
    int b = blockIdx.x, t = threadIdx.x;
    int base = b * BUCKCAP;
    int v[4]; int s = 0;                  // supports nblk <= 1024
#pragma unroll
    for (int j = 0; j < 4; ++j) {
        int idx = t * 4 + j;
        v[j] = (idx < nblk) ? bh[b * nblk + idx] : 0;
        s += v[j];
    }
    sh[t] = s;
    __syncthreads();
    for (int off = 1; off < 256; off <<= 1) {
        int x = (t >= off) ? sh[t - off] : 0;
        __syncthreads();
        sh[t] += x;
        __syncthreads();
    }
    int run = sh[t] - s;
    if (t == 255) btot[b] = (sh[255] < BUCKCAP) ? sh[255] : BUCKCAP;  // safety clamp
#pragma unroll
    for (int j = 0; j < 4; ++j) {
        int idx = t * 4 + j;
        if (idx < nblk) bh[b * nblk + idx] = base + run;
        run += v[j];
    }
}

// ---------- Pass B: scatter packed (local,src) into private (block,bucket) runs ----------
__global__ __launch_bounds__(256) void part_scatter(
    const int* __restrict__ src, const int* __restrict__ dst,
    const int* __restrict__ bh, unsigned int* __restrict__ buf,
    int E, int nblk, int NB2) {
    __shared__ int lbase[256];
    __shared__ int lcnt[256];
    int k = blockIdx.x, t = threadIdx.x;
    lcnt[t] = 0;
    if (t < NB2) lbase[t] = bh[t * nblk + k];
    __syncthreads();
    const int4* dp = (const int4*)(dst + k * EPB);
    const int4* sp = (const int4*)(src + k * EPB);
#pragma unroll
    for (int j = 0; j < EPB / 1024; ++j) {
        int idx = j * 256 + t;
        int e = k * EPB + idx * 4;
        if (e < E) {
            int4 d4 = dp[idx];
            int4 s4 = sp[idx];
            int d, bkt, p;
            d = d4.x; bkt = d >> SB2; p = lbase[bkt] + atomicAdd(&lcnt[bkt], 1);
            buf[p] = ((unsigned int)(d & 511) << 23) | (unsigned int)s4.x;
            d = d4.y; bkt = d >> SB2; p = lbase[bkt] + atomicAdd(&lcnt[bkt], 1);
            buf[p] = ((unsigned int)(d & 511) << 23) | (unsigned int)s4.y;
            d = d4.z; bkt = d >> SB2; p = lbase[bkt] + atomicAdd(&lcnt[bkt], 1);
            buf[p] = ((unsigned int)(d & 511) << 23) | (unsigned int)s4.z;
            d = d4.w; bkt = d >> SB2; p = lbase[bkt] + atomicAdd(&lcnt[bkt], 1);
            buf[p] = ((unsigned int)(d & 511) << 23) | (unsigned int)s4.w;
        }
    }
}

// ---------- Pass C: per bucket — node hist, scan, rptr/rdeg/dinv, csr scatter ----------
__global__ __launch_bounds__(256) void csr_finalize(
    const unsigned int* __restrict__ buf, const int* __restrict__ btot,
    int* __restrict__ rptr, int* __restrict__ rdeg, float* __restrict__ dinv,
    int* __restrict__ csr, int N) {
    __shared__ int hist[1 << SB2];        // 512
    __shared__ int excl[1 << SB2];
    __shared__ int ssc[256];
    int b = blockIdx.x, t = threadIdx.x;
    int nb0 = b << SB2;
    int nn = N - nb0; if (nn > (1 << SB2)) nn = 1 << SB2;
    int beg = b * BUCKCAP;
    int end = beg + btot[b];

    hist[t] = 0; hist[t + 256] = 0;
    __syncthreads();
    for (int i = beg + t; i < end; i += 256)
        atomicAdd(&hist[buf[i] >> 23], 1);
    __syncthreads();

    int a0 = hist[2 * t], a1 = hist[2 * t + 1];
    int s = a0 + a1;
    ssc[t] = s;
    __syncthreads();
    for (int off = 1; off < 256; off <<= 1) {
        int x = (t >= off) ? ssc[t - off] : 0;
        __syncthreads();
        ssc[t] += x;
        __syncthreads();
    }
    int run = ssc[t] - s;
    excl[2 * t] = run;
    excl[2 * t + 1] = run + a0;
    __syncthreads();

    for (int j = t; j < nn; j += 256) {
        rptr[nb0 + j] = beg + excl[j];
        rdeg[nb0 + j] = hist[j];
        dinv[nb0 + j] = rsqrtf((float)hist[j] + 1.0f);   // +1 self-loop
    }
    __syncthreads();

    hist[t] = 0; hist[t + 256] = 0;
    __syncthreads();
    for (int i = beg + t; i < end; i += 256) {
        unsigned int w = buf[i];
        int local = w >> 23;
        int p = beg + excl[local] + atomicAdd(&hist[local], 1);
        csr[p] = (int)(w & 0x7fffffu);
    }
}

// ---------- MFMA GEMM: hs(bf16, stride HSTRIDE) = (A @ W) * d_inv[row] ----------
template<int K, int NOUT, int HSTRIDE, bool AFP32>
__global__ __launch_bounds__(256) void gemm_mfma(
    const void* __restrict__ Aptr, const float* __restrict__ W,
    const float* __restrict__ d_inv, unsigned short* __restrict__ hs, int M)
{
    __shared__ unsigned short Wt[64][K + 8];   // [col][k], +8 pad: <=2-way LDS alias
    __shared__ float Cst[64][68];              // epilogue staging

    const int t = threadIdx.x;
    const int wave = t >> 6, lane = t & 63;
    const int m = lane & 15, kq = lane >> 4;

    for (int idx = t; idx < K * 64; idx += 256) {
        int k = idx >> 6, c = idx & 63;
        float wv = (c < NOUT) ? W[k * NOUT + c] : 0.0f;
        Wt[c][k] = bf_rne(wv);
    }
    __syncthreads();

    const int rb = blockIdx.x * 64;
    int arow = rb + wave * 16 + m;
    if (arow >= M) arow = M - 1;               // clamp (stores are guarded)

    f32x4 acc[4] = {{0.f,0.f,0.f,0.f},{0.f,0.f,0.f,0.f},
                    {0.f,0.f,0.f,0.f},{0.f,0.f,0.f,0.f}};
    union Frag { bf16x8 v; unsigned short u[8]; };

#pragma unroll
    for (int kc = 0; kc < K / 32; ++kc) {
        const int kbase = kc * 32 + kq * 8;
        Frag a;
        if (AFP32) {
            const float* ap = (const float*)Aptr + (size_t)arow * K + kbase;
            float4 x0 = *(const float4*)ap;
            float4 x1 = *(const float4*)(ap + 4);
            a.u[0] = bf_rne(x0.x); a.u[1] = bf_rne(x0.y);
            a.u[2] = bf_rne(x0.z); a.u[3] = bf_rne(x0.w);
            a.u[4] = bf_rne(x1.x); a.u[5] = bf_rne(x1.y);
            a.u[6] = bf_rne(x1.z); a.u[7] = bf_rne(x1.w);
        } else {
            const unsigned short* ap = (const unsigned short*)Aptr + (size_t)arow * 64 + kbase;
            a.v = *(const bf16x8*)ap;
        }
#pragma unroll
        for (int ct = 0; ct < 4; ++ct) {
            Frag b;
            b.v = *(const bf16x8*)(&Wt[ct * 16 + m][kbase]);
            acc[ct] = __builtin_amdgcn_mfma_f32_16x16x32_bf16(a.v, b.v, acc[ct], 0, 0, 0);
        }
    }

#pragma unroll
    for (int ct = 0; ct < 4; ++ct)
#pragma unroll
        for (int r = 0; r < 4; ++r)
            Cst[wave * 16 + kq * 4 + r][ct * 16 + m] = acc[ct][r];
    __syncthreads();

    int row = t >> 2, seg = t & 3;
    int grow = rb + row;
    int c0 = seg * 16;
    if (grow < M && c0 < NOUT) {
        float di = d_inv[grow];
        unsigned int uu[8];
#pragma unroll
        for (int j = 0; j < 8; ++j) {
            float v0 = Cst[row][c0 + 2 * j]     * di;
            float v1 = Cst[row][c0 + 2 * j + 1] * di;
            uu[j] = pk(bf_rne(v0), bf_rne(v1));
        }
        unsigned short* orow = hs + (size_t)grow * HSTRIDE + c0;
        *(uint4*)orow = make_uint4(uu[0], uu[1], uu[2], uu[3]);
        if (NOUT - c0 > 8)
            *((uint4*)orow + 1) = make_uint4(uu[4], uu[5], uu[6], uu[7]);
    }
}

// ---------- fused aggregate + epilogue: quarter-wave per node ----------
// lane = sub*16 + q. Lane owns dims [q*4, q*4+4): private accumulate, no
// reduce. Gather batched 8-deep: 8 independent loads in flight per lane.
// dinv/bias prefetched above the edge loop (latency hides under gathers).
template<int DACT, int HSTRIDE, bool RELU, bool OBF16, int OSTRIDE>
__global__ __launch_bounds__(256) void agg4(
    const unsigned short* __restrict__ hs, const int* __restrict__ rptr,
    const int* __restrict__ rdeg, const int* __restrict__ csr,
    const float* __restrict__ dinv, const float* __restrict__ b,
    void* __restrict__ out, int N)
{
    int i = (blockIdx.x * 256 + threadIdx.x) >> 4;     // node per quarter-wave
    if (i >= N) return;
    int lane = threadIdx.x & 63;
    int q  = lane & 15;                                 // dim quad
    int sb = lane & 48;                                 // subgroup base lane
    constexpr int QACT = DACT / 4;                      // active quads (16 or 10)
    const bool act = (q < QACT);

    int beg = rptr[i];
    int end = beg + rdeg[i];

    float a0 = 0.f, a1 = 0.f, a2 = 0.f, a3 = 0.f;
    float di = 0.f;
    float4 bv = make_float4(0.f, 0.f, 0.f, 0.f);
    if (act) {                                          // self-loop init + prefetch
        di = dinv[i];
        bv = *(const float4*)(b + q * 4);
        uint2 u0 = *(const uint2*)(hs + (size_t)i * HSTRIDE + q * 4);
        a0 = __uint_as_float(u0.x << 16);
        a1 = __uint_as_float(u0.x & 0xffff0000u);
        a2 = __uint_as_float(u0.y << 16);
        a3 = __uint_as_float(u0.y & 0xffff0000u);
    }

    for (int c = beg; c < end; c += 16) {
        int s_l = (c + q < end) ? csr[c + q] : 0;      // coalesced 64B prefetch
        int m = end - c; if (m > 16) m = 16;
        int k = 0;
        for (; k + 8 <= m; k += 8) {                   // 8 loads in flight
            int ss[8];
#pragma unroll
            for (int j = 0; j < 8; ++j) ss[j] = __shfl(s_l, sb | (k + j), 64);
            if (act) {
                uint2 vv[8];
#pragma unroll
                for (int j = 0; j < 8; ++j)
                    vv[j] = *(const uint2*)(hs + (size_t)ss[j] * HSTRIDE + q * 4);
#pragma unroll
                for (int j = 0; j < 8; ++j) {
                    a0 += __uint_as_float(vv[j].x << 16);
                    a1 += __uint_as_float(vv[j].x & 0xffff0000u);
                    a2 += __uint_as_float(vv[j].y << 16);
                    a3 += __uint_as_float(vv[j].y & 0xffff0000u);
                }
            }
        }
        for (; k < m; ++k) {
            int s = __shfl(s_l, sb | k, 64);
            if (act) {
                uint2 u = *(const uint2*)(hs + (size_t)s * HSTRIDE + q * 4);
                a0 += __uint_as_float(u.x << 16);
                a1 += __uint_as_float(u.x & 0xffff0000u);
                a2 += __uint_as_float(u.y << 16);
                a3 += __uint_as_float(u.y & 0xffff0000u);
            }
        }
    }

    if (act) {
        a0 = di * a0 + bv.x; a1 = di * a1 + bv.y;
        a2 = di * a2 + bv.z; a3 = di * a3 + bv.w;
        if (RELU) {
            a0 = fmaxf(a0, 0.f); a1 = fmaxf(a1, 0.f);
            a2 = fmaxf(a2, 0.f); a3 = fmaxf(a3, 0.f);
        }
        if (OBF16) {
            unsigned short* ob = (unsigned short*)out;
            uint2 o;
            o.x = pk(bf_rne(a0), bf_rne(a1));
            o.y = pk(bf_rne(a2), bf_rne(a3));
            *(uint2*)(ob + (size_t)i * 64 + q * 4) = o;
        } else {
            float* of = (float*)out;
            *(float4*)(of + (size_t)i * OSTRIDE + q * 4) = make_float4(a0, a1, a2, a3);
        }
    }
}

extern "C" void kernel_launch(void* const* d_in, const int* in_sizes, int n_in,
                              void* d_out, int out_size, void* d_ws, size_t ws_size,
                              hipStream_t stream) {
    const float* x   = (const float*)d_in[0];
    const int*   ei  = (const int*)  d_in[1];
    const float* W1  = (const float*)d_in[2];
    const float* bb1 = (const float*)d_in[3];
    const float* W2  = (const float*)d_in[4];
    const float* bb2 = (const float*)d_in[5];
    const float* W3  = (const float*)d_in[6];
    const float* bb3 = (const float*)d_in[7];
    float* out = (float*)d_out;

    const int N = in_sizes[0] / 128;      // 100000
    const int E = in_sizes[1] / 2;        // 1600000
    const int* src = ei;
    const int* dst = ei + E;
    const int NB2  = (N + (1 << SB2) - 1) >> SB2;   // 196 buckets (<=256)
    const int nblk = (E + EPB - 1) / EPB;           // 391 partition blocks (<=1024)

    // workspace layout (4-byte units)
    float* ws = (float*)d_ws;
    const size_t NP  = ((size_t)N + 255) & ~255ull;
    float* dinv = ws;                                   // NP
    unsigned short* bufHs  = (unsigned short*)(ws + NP);        // N*64 bf16
    unsigned short* bufAct = bufHs + (size_t)N * 64;            // N*64 bf16
    int*   rptr  = (int*)(bufAct + (size_t)N * 64);     // N
    int*   rdeg  = rptr + N;                            // N
    int*   btot  = rdeg + N;                            // NB2 (pad 256)
    int*   bh    = btot + 256;                          // NB2*nblk
    size_t bhsz  = ((size_t)NB2 * nblk + 1) & ~1ull;
    unsigned int* buf = (unsigned int*)(bh + bhsz);     // NB2*BUCKCAP
    int*   csr   = (int*)(buf + (size_t)NB2 * BUCKCAP); // NB2*BUCKCAP
    int*   bar   = csr + (size_t)NB2 * BUCKCAP;         // unused (kept for layout stability)
    (void)bar;

    dim3 blk(BLK);
    int gRows = (N + 63) / 64;
    int gQW   = (N * 16 + BLK - 1) / BLK;    // quarter-wave per node

    // ---- binned partition -> CSR + degrees ----
    part_hist<<<nblk, blk, 0, stream>>>(dst, bh, E, nblk, NB2);
    part_scan<<<NB2, blk, 0, stream>>>(bh, btot, nblk);
    part_scatter<<<nblk, blk, 0, stream>>>(src, dst, bh, buf, E, nblk, NB2);
    csr_finalize<<<NB2, blk, 0, stream>>>(buf, btot, rptr, rdeg, dinv, csr, N);

    // ---- layer 1: 128 -> 64, relu ----
    gemm_mfma<128, 64, 64, true><<<gRows, blk, 0, stream>>>(x, W1, dinv, bufHs, N);
    agg4<64, 64, true, true, 64><<<gQW, blk, 0, stream>>>(bufHs, rptr, rdeg, csr, dinv, bb1, bufAct, N);

    // ---- layer 2: 64 -> 64, relu ----
    gemm_mfma<64, 64, 64, false><<<gRows, blk, 0, stream>>>(bufAct, W2, dinv, bufHs, N);
    agg4<64, 64, true, true, 64><<<gQW, blk, 0, stream>>>(bufHs, rptr, rdeg, csr, dinv, bb2, bufAct, N);

    // ---- layer 3: 64 -> 40 packed stride-40, no relu ----
    gemm_mfma<64, 40, 40, false><<<gRows, blk, 0, stream>>>(bufAct, W3, dinv, bufHs, N);
    agg4<40, 40, false, false, 40><<<gQW, blk, 0, stream>>>(bufHs, rptr, rdeg, csr, dinv, bb3, out, N);
}